// Round 21
// baseline (96.992 us; speedup 1.0000x reference)
//
#include <hip/hip_runtime.h>

#define DEV static __device__ __forceinline__

typedef __attribute__((ext_vector_type(8))) short short8;
typedef __attribute__((ext_vector_type(8))) __bf16 bf16x8;
typedef __attribute__((ext_vector_type(4))) float f32x4;
typedef __attribute__((ext_vector_type(2))) float f32x2;

// N=8 agents, B=8192, OBS=128, ACT=32, D=160, E=128, L=8
//
// pi-layout: within each 128-wide k-chunk, position p = 8*g + m holds actual
// k = 16*m + g (consistently on both MFMA operands).
//
// Register law (R5-R9, R19): never cap VGPRs below live state.
// Work law (R10): v is MFMA'd exactly once; S - v rides in k3's A-build.
// Cache law (R11): workspace tensors are L3-candidates -> no NT hints.
// Transpose law (R17): swap MFMA operands in producers - transpose for free.
// Staging law (R18): LDS B-staging mandatory (bytes cross mem pipe once per
// block, not per wave).
// Slot law (R20): within each (panel,rowtile) tile, slot order
// s' = (gl/4)*64 + row*4 + (gl%4) makes producer stores (lane's 4 granules
// consecutive -> 2-4KB contiguous wave stores) AND consumer loads
// (gl = t*4+kg -> 64 consecutive slots -> 512B/1KB contiguous) all
// single-transaction. Old order gl*16+row gave 4x128B scatter per op.

DEV short f2bf(float f) { return __builtin_bit_cast(short, (__bf16)f); }
DEV float bf2f(short h) {
  unsigned u = ((unsigned)(unsigned short)h) << 16;
  return __builtin_bit_cast(float, u);
}
DEV f32x4 mfma16(short8 a, short8 b, f32x4 c) {
  return __builtin_amdgcn_mfma_f32_16x16x32_bf16(
      __builtin_bit_cast(bf16x8, a), __builtin_bit_cast(bf16x8, b), c, 0, 0, 0);
}
DEV void async_copy16(short* lds, const short* g) {
  __builtin_amdgcn_global_load_lds(
      (const __attribute__((address_space(1))) void*)g,
      (__attribute__((address_space(3))) void*)lds, 16, 0, 0);
}

template <int GPC, int SRC_STRIDE, int LDS_STRIDE>
DEV void stage_bt(short* lds, const short* src, int tid) {
  constexpr int TOTAL = 128 * GPC;
  #pragma unroll
  for (int g0 = 0; g0 < TOTAL; g0 += 256) {
    int g = g0 + tid;
    int c = g / GPC, kg = g % GPC;
    *(short8*)(lds + c * LDS_STRIDE + kg * 8) =
        *(const short8*)(src + c * SRC_STRIDE + kg * 8);
  }
}

// ---- K0: weights fp32 [K][128] -> bf16 [128][K]; Wv/W1 in pi-k order -------
__global__ __launch_bounds__(256) void k0_tr(const float* __restrict__ Wg,
                                             const float* __restrict__ Wv,
                                             const float* __restrict__ W1,
                                             short* __restrict__ WgT,
                                             short* __restrict__ WvP,
                                             short* __restrict__ W1P) {
  int g = blockIdx.x * 256 + threadIdx.x;  // 184320 granules total
  short8 o;
  if (g < 20480) {  // Wg: K=160, natural k
    int n = g / 2560, rem = g % 2560;
    int c = rem & 127, kg = rem >> 7;
    const float* src = Wg + n * 20480;
    #pragma unroll
    for (int j = 0; j < 8; ++j) o[j] = f2bf(src[(size_t)(kg * 8 + j) * 128 + c]);
    *(short8*)(WgT + n * 20480 + c * 160 + kg * 8) = o;
  } else if (g < 36864) {  // Wv: K=128, pi order
    int g2 = g - 20480;
    int n = g2 >> 11, rem = g2 & 2047;
    int c = rem & 127, kg = rem >> 7;
    const float* src = Wv + n * 16384;
    #pragma unroll
    for (int j = 0; j < 8; ++j) o[j] = f2bf(src[(size_t)(16 * j + kg) * 128 + c]);
    *(short8*)(WvP + n * 16384 + c * 128 + kg * 8) = o;
  } else {  // W1: K=1152, pi order within each 128-chunk
    int g3 = g - 36864;
    int n = g3 / 18432, rem = g3 % 18432;
    int c = rem & 127, kg = rem >> 7;
    int chunk = kg >> 4, kl = kg & 15;
    const float* src = W1 + (size_t)n * 147456;
    #pragma unroll
    for (int j = 0; j < 8; ++j)
      o[j] = f2bf(src[(size_t)(chunk * 128 + 16 * j + kl) * 128 + c]);
    *(short8*)(W1P + (size_t)n * 147456 + c * 1152 + kg * 8) = o;
  }
}

// ---- K1: e = relu(oa @ Wg + bg) -> eA (A-frag, s' slot order), swapped
//      MFMA; lane's 4 granules stored at consecutive slots (64B/lane). -----
__global__ __launch_bounds__(256) void k1_e(const float* __restrict__ obs,
                                            const float* __restrict__ act,
                                            const short* __restrict__ WgT,
                                            const float* __restrict__ bg,
                                            short* __restrict__ eA) {
  __shared__ __align__(16) short BW[128 * 168];
  const int btile = blockIdx.x, n = blockIdx.y, tid = threadIdx.x;
  stage_bt<20, 160, 168>(BW, WgT + n * 20480, tid);
  __syncthreads();
  const int lane = tid & 63, wave = tid >> 6, lr = lane & 15, kg = lane >> 4;
  const int rowbase = btile * 64 + wave * 16;
  const int rowtile = btile * 4 + wave;
  f32x4 acc[8];
  #pragma unroll
  for (int m = 0; m < 8; ++m) acc[m] = f32x4{0.f, 0.f, 0.f, 0.f};
  const float* obsp = obs + (size_t)(n * 8192 + rowbase + lr) * 128;
  const float* actp = act + (size_t)(n * 8192 + rowbase + lr) * 32;
  #pragma unroll
  for (int ks = 0; ks < 5; ++ks) {
    const float* ap = (ks < 4) ? (obsp + ks * 32 + kg * 8) : (actp + kg * 8);
    float4 p0 = *(const float4*)ap;
    float4 p1 = *(const float4*)(ap + 4);
    short8 a;
    a[0] = f2bf(p0.x); a[1] = f2bf(p0.y); a[2] = f2bf(p0.z); a[3] = f2bf(p0.w);
    a[4] = f2bf(p1.x); a[5] = f2bf(p1.y); a[6] = f2bf(p1.z); a[7] = f2bf(p1.w);
    #pragma unroll
    for (int m = 0; m < 8; ++m) {
      short8 b = *(const short8*)(&BW[(m * 16 + lr) * 168 + ks * 32 + kg * 8]);
      acc[m] = mfma16(b, a, acc[m]);  // swapped: C = (oa@Wg)^T per-lane
    }
  }
  f32x4 bg4[8];
  #pragma unroll
  for (int m = 0; m < 8; ++m)
    bg4[m] = *(const f32x4*)(bg + n * 128 + m * 16 + kg * 4);
  #pragma unroll
  for (int r = 0; r < 4; ++r) {
    short8 pkt;  // A-granule (row=lr, gl=kg*4+r): elements m=0..7
    #pragma unroll
    for (int m = 0; m < 8; ++m) {
      float x = acc[m][r] + bg4[m][r];
      pkt[m] = f2bf(x > 0.f ? x : 0.f);
    }
    *(short8*)(eA + ((size_t)(n * 512 + rowtile) * 256 + kg * 64 + lr * 4 +
                     r) * 8) = pkt;
  }
}

// ---- K2V: per (btile,l): v_j = leaky(e_j@Wv_l+bv_l) -> VBf (fp8, s' order,
//      32B/lane contiguous stores), S -> SBf (bf16, 64B/lane contiguous).
//      Swapped MFMA; e[j+1] prefetch. 1D grid bid = l*128+btile. -----------
__global__ __launch_bounds__(256) void k2_V(const short* __restrict__ eA,
                                            const short* __restrict__ WvP,
                                            const float* __restrict__ bv,
                                            short* __restrict__ SBf,
                                            unsigned char* __restrict__ VBf) {
  __shared__ __align__(16) short BW[128 * 136];
  const int bid = blockIdx.x;
  const int l = bid >> 7, btile = bid & 127;
  const int tid = threadIdx.x;
  stage_bt<16, 128, 136>(BW, WvP + l * 16384, tid);
  __syncthreads();
  const int lane = tid & 63, wave = tid >> 6, lr = lane & 15, kg = lane >> 4;
  const int rowtile = btile * 4 + wave;
  f32x4 bvv4[8];
  #pragma unroll
  for (int m = 0; m < 8; ++m)
    bvv4[m] = *(const f32x4*)(bv + l * 128 + m * 16 + kg * 4);
  f32x4 Sacc[8];
  #pragma unroll
  for (int m = 0; m < 8; ++m) Sacc[m] = f32x4{0.f, 0.f, 0.f, 0.f};
  short8 a[4], an[4];
  #pragma unroll
  for (int ks = 0; ks < 4; ++ks)  // j=0: gl=ks*4+kg -> slot ks*64+lr*4+kg
    a[ks] = *(const short8*)(
        eA + ((size_t)rowtile * 256 + ks * 64 + lr * 4 + kg) * 8);
  for (int j = 0; j < 8; ++j) {
    if (j + 1 < 8) {  // prefetch e[j+1]
      #pragma unroll
      for (int ks = 0; ks < 4; ++ks)
        an[ks] = *(const short8*)(
            eA + ((size_t)((j + 1) * 512 + rowtile) * 256 + ks * 64 + lr * 4 +
                  kg) * 8);
    }
    f32x4 acc[8];
    #pragma unroll
    for (int m = 0; m < 8; ++m) acc[m] = f32x4{0.f, 0.f, 0.f, 0.f};
    #pragma unroll
    for (int ks = 0; ks < 4; ++ks)
      #pragma unroll
      for (int m = 0; m < 8; ++m) {
        short8 b = *(const short8*)(&BW[(m * 16 + lr) * 136 + ks * 32 + kg * 8]);
        acc[m] = mfma16(b, a[ks], acc[m]);  // swapped: v^T C-layout
      }
    #pragma unroll
    for (int r = 0; r < 4; ++r) {
      float x[8];
      #pragma unroll
      for (int m = 0; m < 8; ++m) {
        float t = acc[m][r] + bvv4[m][r];
        t = (t > 0.f) ? t : 0.01f * t;  // leaky_relu
        Sacc[m][r] += t;
        x[m] = t;
      }
      unsigned lo = 0, hi = 0;
      lo = __builtin_amdgcn_cvt_pk_fp8_f32(x[0], x[1], lo, false);
      lo = __builtin_amdgcn_cvt_pk_fp8_f32(x[2], x[3], lo, true);
      hi = __builtin_amdgcn_cvt_pk_fp8_f32(x[4], x[5], hi, false);
      hi = __builtin_amdgcn_cvt_pk_fp8_f32(x[6], x[7], hi, true);
      uint2 o{lo, hi};
      // gl=kg*4+r -> slot kg*64 + lr*4 + r (4 consecutive per lane)
      *(uint2*)(VBf + ((size_t)((j * 8 + l) * 512 + rowtile) * 256 + kg * 64 +
                       lr * 4 + r) * 8) = o;
    }
    #pragma unroll
    for (int ks = 0; ks < 4; ++ks) a[ks] = an[ks];
  }
  #pragma unroll
  for (int r = 0; r < 4; ++r) {
    short8 pkt;
    #pragma unroll
    for (int m = 0; m < 8; ++m) pkt[m] = f2bf(Sacc[m][r]);
    *(short8*)(SBf + ((size_t)(l * 512 + rowtile) * 256 + kg * 64 + lr * 4 +
                      r) * 8) = pkt;
  }
}

// ---- K3H: per agent, streaming GEMM, BK=64, 18 chunks, 256thr/4 waves/64
//      rows, LDS dbuf 2x16KB -> 4 blocks/CU. s'-order operand loads: sv 1KB,
//      vv 512B fully contiguous. Chunks 0..15: A=bf16(S)-fp8(v); 16,17: e. --
__global__ __launch_bounds__(256, 4) void k3_h(const short* __restrict__ eA,
                                               const short* __restrict__ SBf,
                                               const unsigned char* __restrict__ VBf,
                                               const short* __restrict__ W1P,
                                               const float* __restrict__ b1,
                                               const float* __restrict__ W2,
                                               const float* __restrict__ b2,
                                               float* __restrict__ out) {
  __shared__ __align__(16) short BW[2][128 * 64];  // 2 x 16KB
  const int bid = blockIdx.x;
  const int i = bid & 7;        // agent -> XCD pinning
  const int btile = bid >> 3;   // 128 btiles x 64 rows
  const int tid = threadIdx.x;  // 256 threads, 4 waves
  const int lane = tid & 63, wave = tid >> 6, lr = lane & 15, kg = lane >> 4;
  const int lr8 = lane & 7;
  const int rowbase = btile * 64 + wave * 16;
  const int rowtile = btile * 4 + wave;
  const short* w1 = W1P + (size_t)i * 147456;

#define STAGE_W1(buf, koff)                                                    \
  {                                                                            \
    _Pragma("unroll") for (int t = 0; t < 4; ++t) {                            \
      int G = t * 256 + tid;                                                   \
      int cG = G >> 3, gl = G & 7;                                             \
      async_copy16((buf) + (t * 256 + wave * 64) * 8,                          \
                   w1 + cG * 1152 + (koff) + ((gl ^ (cG & 7)) << 3));          \
    }                                                                          \
  }

  short8 sv[2];
  uint2 vv[2];
  #pragma unroll
  for (int ks = 0; ks < 2; ++ks) {  // chunk 0 (l=0,h=0): slot ks*64+lr*4+kg
    sv[ks] = *(const short8*)(
        SBf + ((size_t)rowtile * 256 + ks * 64 + lr * 4 + kg) * 8);
    vv[ks] = *(const uint2*)(
        VBf + ((size_t)((i * 8) * 512 + rowtile) * 256 + ks * 64 + lr * 4 +
               kg) * 8);
  }
  f32x4 hacc[8];
  #pragma unroll
  for (int m = 0; m < 8; ++m) hacc[m] = f32x4{0.f, 0.f, 0.f, 0.f};

  STAGE_W1(BW[0], 0);
  for (int c = 0; c < 18; ++c) {
    __syncthreads();  // stage(c) drained; BW[(c+1)&1] free
    if (c < 17) { STAGE_W1(BW[(c + 1) & 1], (c + 1) * 64); }
    short8 aa[2];
    if (c < 16) {
      #pragma unroll
      for (int ks = 0; ks < 2; ++ks) {
        f32x2 f01 = __builtin_amdgcn_cvt_pk_f32_fp8((int)vv[ks].x, false);
        f32x2 f23 = __builtin_amdgcn_cvt_pk_f32_fp8((int)vv[ks].x, true);
        f32x2 f45 = __builtin_amdgcn_cvt_pk_f32_fp8((int)vv[ks].y, false);
        f32x2 f67 = __builtin_amdgcn_cvt_pk_f32_fp8((int)vv[ks].y, true);
        aa[ks][0] = f2bf(bf2f(sv[ks][0]) - f01.x);
        aa[ks][1] = f2bf(bf2f(sv[ks][1]) - f01.y);
        aa[ks][2] = f2bf(bf2f(sv[ks][2]) - f23.x);
        aa[ks][3] = f2bf(bf2f(sv[ks][3]) - f23.y);
        aa[ks][4] = f2bf(bf2f(sv[ks][4]) - f45.x);
        aa[ks][5] = f2bf(bf2f(sv[ks][5]) - f45.y);
        aa[ks][6] = f2bf(bf2f(sv[ks][6]) - f67.x);
        aa[ks][7] = f2bf(bf2f(sv[ks][7]) - f67.y);
      }
    } else {
      aa[0] = sv[0];  // e half-fragments (prefetched at c-1)
      aa[1] = sv[1];
    }
    // prefetch chunk c+1 operands: slot (h*2+ks)*64 + lr*4 + kg
    if (c + 1 < 16) {
      int l = (c + 1) >> 1, h = (c + 1) & 1;
      #pragma unroll
      for (int ks = 0; ks < 2; ++ks) {
        sv[ks] = *(const short8*)(
            SBf + (((size_t)l * 512 + rowtile) * 256 + (h * 2 + ks) * 64 +
                   lr * 4 + kg) * 8);
        vv[ks] = *(const uint2*)(
            VBf + (((size_t)(i * 8 + l) * 512 + rowtile) * 256 +
                   (h * 2 + ks) * 64 + lr * 4 + kg) * 8);
      }
    } else if (c + 1 < 18) {
      int h = c + 1 - 16;
      #pragma unroll
      for (int ks = 0; ks < 2; ++ks)
        sv[ks] = *(const short8*)(
            eA + (((size_t)i * 512 + rowtile) * 256 + (h * 2 + ks) * 64 +
                  lr * 4 + kg) * 8);
    }
    const short* bw = BW[c & 1];
    #pragma unroll
    for (int ks = 0; ks < 2; ++ks)
      #pragma unroll
      for (int m = 0; m < 8; ++m) {
        short8 b = *(const short8*)(bw + (m * 16 + lr) * 64 +
                                    (((ks * 4 + kg) ^ lr8) << 3));
        hacc[m] = mfma16(aa[ks], b, hacc[m]);
      }
  }
#undef STAGE_W1

  // epilogue: h = relu(hacc + b1); out = h . W2 + b2
  float sacc[4] = {0.f, 0.f, 0.f, 0.f};
  #pragma unroll
  for (int m = 0; m < 8; ++m) {
    int col = m * 16 + lr;
    float b1v = b1[i * 128 + col];
    float w2v = W2[i * 128 + col];
    #pragma unroll
    for (int r = 0; r < 4; ++r) {
      float h = hacc[m][r] + b1v;
      h = h > 0.f ? h : 0.f;
      sacc[r] += h * w2v;
    }
  }
  #pragma unroll
  for (int r = 0; r < 4; ++r) {
    float v = sacc[r];
    v += __shfl_xor(v, 1);
    v += __shfl_xor(v, 2);
    v += __shfl_xor(v, 4);
    v += __shfl_xor(v, 8);
    if (lr == 0) out[i * 8192 + rowbase + kg * 4 + r] = v + b2[i];
  }
}

extern "C" void kernel_launch(void* const* d_in, const int* in_sizes, int n_in,
                              void* d_out, int out_size, void* d_ws, size_t ws_size,
                              hipStream_t stream) {
  const float* obs = (const float*)d_in[0];
  const float* act = (const float*)d_in[1];
  const float* Wg  = (const float*)d_in[2];
  const float* bg  = (const float*)d_in[3];
  // d_in[4..7] = Wq,bq,Wk,bk: dead (softmax over singleton axis == 1)
  const float* Wv  = (const float*)d_in[8];
  const float* bv  = (const float*)d_in[9];
  const float* W1  = (const float*)d_in[10];
  const float* b1  = (const float*)d_in[11];
  const float* W2  = (const float*)d_in[12];
  const float* b2  = (const float*)d_in[13];
  float* out = (float*)d_out;

  const size_t E_N = (size_t)8 * 8192 * 128;    // eA / SBf shorts (8.4M each)
  const size_t V_B = (size_t)64 * 8192 * 128;   // VBf BYTES (fp8, 67.1 MB)
  // ws proven >= 170 MB (R11/R12 fast path ran); need here ~104 MB.

  short* eA  = (short*)d_ws;
  unsigned char* VBf = (unsigned char*)(eA + E_N);
  short* SBf = (short*)(VBf + V_B);
  short* WgT = SBf + E_N;
  short* WvP = WgT + 163840;
  short* W1P = WvP + 131072;

  k0_tr<<<720, 256, 0, stream>>>(Wg, Wv, W1, WgT, WvP, W1P);
  k1_e<<<dim3(128, 8), 256, 0, stream>>>(obs, act, WgT, bg, eA);
  k2_V<<<1024, 256, 0, stream>>>(eA, WvP, bv, SBf, VBf);
  k3_h<<<1024, 256, 0, stream>>>(eA, SBf, VBf, W1P, b1, W2, b2, out);
}

// Round 22
// 93.843 us; speedup vs baseline: 1.0336x; 1.0336x over previous
//
#include <hip/hip_runtime.h>

#define DEV static __device__ __forceinline__

typedef __attribute__((ext_vector_type(8))) short short8;
typedef __attribute__((ext_vector_type(8))) __bf16 bf16x8;
typedef __attribute__((ext_vector_type(4))) float f32x4;
typedef __attribute__((ext_vector_type(2))) float f32x2;

// N=8 agents, B=8192, OBS=128, ACT=32, D=160, E=128, L=8
//
// pi-layout: within each 128-wide k-chunk, position p = 8*g + m holds actual
// k = 16*m + g (consistently on both MFMA operands).
//
// Register law (R5-R9, R19): never cap VGPRs below live state.
// Work law (R10): v is MFMA'd exactly once; S - v rides in k3's A-build.
// Cache law (R11): workspace tensors are L3-candidates -> no NT hints.
// Request law (R15/R16): operand tensors in fragment-major layouts; every
// load/store one contiguous wave transaction.
// Transpose law (R17): swap MFMA operands in producers - transpose for free.
// Staging law (R18): LDS B-staging mandatory (bytes cross mem pipe once per
// block, not per wave).
// Floor law (R21): with fragment-major layouts both hot kernels sit at
// ~2.5-2.6 TB/s effective regardless of slot order / occupancy / barrier
// variants -> structure is at its producer-consumer latency floor (R20
// config = measured best, restored here).

DEV short f2bf(float f) { return __builtin_bit_cast(short, (__bf16)f); }
DEV float bf2f(short h) {
  unsigned u = ((unsigned)(unsigned short)h) << 16;
  return __builtin_bit_cast(float, u);
}
DEV f32x4 mfma16(short8 a, short8 b, f32x4 c) {
  return __builtin_amdgcn_mfma_f32_16x16x32_bf16(
      __builtin_bit_cast(bf16x8, a), __builtin_bit_cast(bf16x8, b), c, 0, 0, 0);
}
DEV void async_copy16(short* lds, const short* g) {
  __builtin_amdgcn_global_load_lds(
      (const __attribute__((address_space(1))) void*)g,
      (__attribute__((address_space(3))) void*)lds, 16, 0, 0);
}

template <int GPC, int SRC_STRIDE, int LDS_STRIDE>
DEV void stage_bt(short* lds, const short* src, int tid) {
  constexpr int TOTAL = 128 * GPC;
  #pragma unroll
  for (int g0 = 0; g0 < TOTAL; g0 += 256) {
    int g = g0 + tid;
    int c = g / GPC, kg = g % GPC;
    *(short8*)(lds + c * LDS_STRIDE + kg * 8) =
        *(const short8*)(src + c * SRC_STRIDE + kg * 8);
  }
}

// ---- K0: weights fp32 [K][128] -> bf16 [128][K]; Wv/W1 in pi-k order -------
__global__ __launch_bounds__(256) void k0_tr(const float* __restrict__ Wg,
                                             const float* __restrict__ Wv,
                                             const float* __restrict__ W1,
                                             short* __restrict__ WgT,
                                             short* __restrict__ WvP,
                                             short* __restrict__ W1P) {
  int g = blockIdx.x * 256 + threadIdx.x;  // 184320 granules total
  short8 o;
  if (g < 20480) {  // Wg: K=160, natural k
    int n = g / 2560, rem = g % 2560;
    int c = rem & 127, kg = rem >> 7;
    const float* src = Wg + n * 20480;
    #pragma unroll
    for (int j = 0; j < 8; ++j) o[j] = f2bf(src[(size_t)(kg * 8 + j) * 128 + c]);
    *(short8*)(WgT + n * 20480 + c * 160 + kg * 8) = o;
  } else if (g < 36864) {  // Wv: K=128, pi order
    int g2 = g - 20480;
    int n = g2 >> 11, rem = g2 & 2047;
    int c = rem & 127, kg = rem >> 7;
    const float* src = Wv + n * 16384;
    #pragma unroll
    for (int j = 0; j < 8; ++j) o[j] = f2bf(src[(size_t)(16 * j + kg) * 128 + c]);
    *(short8*)(WvP + n * 16384 + c * 128 + kg * 8) = o;
  } else {  // W1: K=1152, pi order within each 128-chunk
    int g3 = g - 36864;
    int n = g3 / 18432, rem = g3 % 18432;
    int c = rem & 127, kg = rem >> 7;
    int chunk = kg >> 4, kl = kg & 15;
    const float* src = W1 + (size_t)n * 147456;
    #pragma unroll
    for (int j = 0; j < 8; ++j)
      o[j] = f2bf(src[(size_t)(chunk * 128 + 16 * j + kl) * 128 + c]);
    *(short8*)(W1P + (size_t)n * 147456 + c * 1152 + kg * 8) = o;
  }
}

// ---- K1: e = relu(oa @ Wg + bg) -> eA (A-frag layout), swapped-operand
//      MFMA so each lane's C-output IS its A-granule; coalesced stores. -----
__global__ __launch_bounds__(256) void k1_e(const float* __restrict__ obs,
                                            const float* __restrict__ act,
                                            const short* __restrict__ WgT,
                                            const float* __restrict__ bg,
                                            short* __restrict__ eA) {
  __shared__ __align__(16) short BW[128 * 168];
  const int btile = blockIdx.x, n = blockIdx.y, tid = threadIdx.x;
  stage_bt<20, 160, 168>(BW, WgT + n * 20480, tid);
  __syncthreads();
  const int lane = tid & 63, wave = tid >> 6, lr = lane & 15, kg = lane >> 4;
  const int rowbase = btile * 64 + wave * 16;
  const int rowtile = btile * 4 + wave;
  f32x4 acc[8];
  #pragma unroll
  for (int m = 0; m < 8; ++m) acc[m] = f32x4{0.f, 0.f, 0.f, 0.f};
  const float* obsp = obs + (size_t)(n * 8192 + rowbase + lr) * 128;
  const float* actp = act + (size_t)(n * 8192 + rowbase + lr) * 32;
  #pragma unroll
  for (int ks = 0; ks < 5; ++ks) {
    const float* ap = (ks < 4) ? (obsp + ks * 32 + kg * 8) : (actp + kg * 8);
    float4 p0 = *(const float4*)ap;
    float4 p1 = *(const float4*)(ap + 4);
    short8 a;
    a[0] = f2bf(p0.x); a[1] = f2bf(p0.y); a[2] = f2bf(p0.z); a[3] = f2bf(p0.w);
    a[4] = f2bf(p1.x); a[5] = f2bf(p1.y); a[6] = f2bf(p1.z); a[7] = f2bf(p1.w);
    #pragma unroll
    for (int m = 0; m < 8; ++m) {
      short8 b = *(const short8*)(&BW[(m * 16 + lr) * 168 + ks * 32 + kg * 8]);
      acc[m] = mfma16(b, a, acc[m]);  // swapped: C = (oa@Wg)^T per-lane
    }
  }
  f32x4 bg4[8];
  #pragma unroll
  for (int m = 0; m < 8; ++m)
    bg4[m] = *(const f32x4*)(bg + n * 128 + m * 16 + kg * 4);
  #pragma unroll
  for (int r = 0; r < 4; ++r) {
    short8 pkt;  // A-granule (row=lr, g=kg*4+r): elements m=0..7
    #pragma unroll
    for (int m = 0; m < 8; ++m) {
      float x = acc[m][r] + bg4[m][r];
      pkt[m] = f2bf(x > 0.f ? x : 0.f);
    }
    *(short8*)(eA + ((size_t)(n * 512 + rowtile) * 256 + (kg * 4 + r) * 16 +
                     lr) * 8) = pkt;
  }
}

// ---- K2V: per (btile,l): v_j = leaky(e_j@Wv_l+bv_l) -> VBf (fp8, A-frag),
//      S = sum_j v_j -> SBf (bf16, A-frag). Swapped MFMA; e[j+1] prefetch
//      (hides e-load latency at ~3 waves/SIMD). 1D grid: bid = l*128+btile
//      so all 8 l-blocks of one btile land on XCD (btile%8) -> eA panel in
//      one L2. No launch_bounds cap (R19 spill lesson). --------------------
__global__ __launch_bounds__(256) void k2_V(const short* __restrict__ eA,
                                            const short* __restrict__ WvP,
                                            const float* __restrict__ bv,
                                            short* __restrict__ SBf,
                                            unsigned char* __restrict__ VBf) {
  __shared__ __align__(16) short BW[128 * 136];
  const int bid = blockIdx.x;
  const int l = bid >> 7, btile = bid & 127;
  const int tid = threadIdx.x;
  stage_bt<16, 128, 136>(BW, WvP + l * 16384, tid);
  __syncthreads();
  const int lane = tid & 63, wave = tid >> 6, lr = lane & 15, kg = lane >> 4;
  const int rowtile = btile * 4 + wave;
  f32x4 bvv4[8];
  #pragma unroll
  for (int m = 0; m < 8; ++m)
    bvv4[m] = *(const f32x4*)(bv + l * 128 + m * 16 + kg * 4);
  f32x4 Sacc[8];
  #pragma unroll
  for (int m = 0; m < 8; ++m) Sacc[m] = f32x4{0.f, 0.f, 0.f, 0.f};
  short8 a[4], an[4];
  #pragma unroll
  for (int ks = 0; ks < 4; ++ks)
    a[ks] = *(const short8*)(
        eA + ((size_t)rowtile * 256 + ks * 64 + lane) * 8);  // j=0
  for (int j = 0; j < 8; ++j) {
    if (j + 1 < 8) {  // prefetch e[j+1]
      #pragma unroll
      for (int ks = 0; ks < 4; ++ks)
        an[ks] = *(const short8*)(
            eA + ((size_t)((j + 1) * 512 + rowtile) * 256 + ks * 64 + lane) * 8);
    }
    f32x4 acc[8];
    #pragma unroll
    for (int m = 0; m < 8; ++m) acc[m] = f32x4{0.f, 0.f, 0.f, 0.f};
    #pragma unroll
    for (int ks = 0; ks < 4; ++ks)
      #pragma unroll
      for (int m = 0; m < 8; ++m) {
        short8 b = *(const short8*)(&BW[(m * 16 + lr) * 136 + ks * 32 + kg * 8]);
        acc[m] = mfma16(b, a[ks], acc[m]);  // swapped: v^T C-layout
      }
    #pragma unroll
    for (int r = 0; r < 4; ++r) {
      float x[8];
      #pragma unroll
      for (int m = 0; m < 8; ++m) {
        float t = acc[m][r] + bvv4[m][r];
        t = (t > 0.f) ? t : 0.01f * t;  // leaky_relu
        Sacc[m][r] += t;
        x[m] = t;
      }
      unsigned lo = 0, hi = 0;
      lo = __builtin_amdgcn_cvt_pk_fp8_f32(x[0], x[1], lo, false);
      lo = __builtin_amdgcn_cvt_pk_fp8_f32(x[2], x[3], lo, true);
      hi = __builtin_amdgcn_cvt_pk_fp8_f32(x[4], x[5], hi, false);
      hi = __builtin_amdgcn_cvt_pk_fp8_f32(x[6], x[7], hi, true);
      uint2 o{lo, hi};
      *(uint2*)(VBf + ((size_t)((j * 8 + l) * 512 + rowtile) * 256 +
                       (kg * 4 + r) * 16 + lr) * 8) = o;
    }
    #pragma unroll
    for (int ks = 0; ks < 4; ++ks) a[ks] = an[ks];
  }
  #pragma unroll
  for (int r = 0; r < 4; ++r) {
    short8 pkt;
    #pragma unroll
    for (int m = 0; m < 8; ++m) pkt[m] = f2bf(Sacc[m][r]);
    *(short8*)(SBf + ((size_t)(l * 512 + rowtile) * 256 + (kg * 4 + r) * 16 +
                      lr) * 8) = pkt;
  }
}

// ---- K3H: per agent, streaming GEMM, BK=64, 18 chunks, 256thr/4 waves/64
//      rows, LDS dbuf 2x16KB -> 4 blocks/CU. All operand loads coalesced
//      (A-frag layout). Chunks 0..15: A = bf16(S)-fp8(v); 16,17: A = e. ----
__global__ __launch_bounds__(256, 4) void k3_h(const short* __restrict__ eA,
                                               const short* __restrict__ SBf,
                                               const unsigned char* __restrict__ VBf,
                                               const short* __restrict__ W1P,
                                               const float* __restrict__ b1,
                                               const float* __restrict__ W2,
                                               const float* __restrict__ b2,
                                               float* __restrict__ out) {
  __shared__ __align__(16) short BW[2][128 * 64];  // 2 x 16KB
  const int bid = blockIdx.x;
  const int i = bid & 7;        // agent -> XCD pinning
  const int btile = bid >> 3;   // 128 btiles x 64 rows
  const int tid = threadIdx.x;  // 256 threads, 4 waves
  const int lane = tid & 63, wave = tid >> 6, lr = lane & 15, kg = lane >> 4;
  const int lr8 = lane & 7;
  const int rowbase = btile * 64 + wave * 16;
  const int rowtile = btile * 4 + wave;
  const short* w1 = W1P + (size_t)i * 147456;

#define STAGE_W1(buf, koff)                                                    \
  {                                                                            \
    _Pragma("unroll") for (int t = 0; t < 4; ++t) {                            \
      int G = t * 256 + tid;                                                   \
      int cG = G >> 3, gl = G & 7;                                             \
      async_copy16((buf) + (t * 256 + wave * 64) * 8,                          \
                   w1 + cG * 1152 + (koff) + ((gl ^ (cG & 7)) << 3));          \
    }                                                                          \
  }

  short8 sv[2];
  uint2 vv[2];
  #pragma unroll
  for (int ks = 0; ks < 2; ++ks) {  // prefetch chunk 0 (l=0, h=0)
    sv[ks] = *(const short8*)(
        SBf + ((size_t)rowtile * 256 + ks * 64 + lane) * 8);
    vv[ks] = *(const uint2*)(
        VBf + ((size_t)((i * 8) * 512 + rowtile) * 256 + ks * 64 + lane) * 8);
  }
  f32x4 hacc[8];
  #pragma unroll
  for (int m = 0; m < 8; ++m) hacc[m] = f32x4{0.f, 0.f, 0.f, 0.f};

  STAGE_W1(BW[0], 0);
  for (int c = 0; c < 18; ++c) {
    __syncthreads();  // stage(c) drained; BW[(c+1)&1] free
    if (c < 17) { STAGE_W1(BW[(c + 1) & 1], (c + 1) * 64); }
    short8 aa[2];
    if (c < 16) {
      #pragma unroll
      for (int ks = 0; ks < 2; ++ks) {
        f32x2 f01 = __builtin_amdgcn_cvt_pk_f32_fp8((int)vv[ks].x, false);
        f32x2 f23 = __builtin_amdgcn_cvt_pk_f32_fp8((int)vv[ks].x, true);
        f32x2 f45 = __builtin_amdgcn_cvt_pk_f32_fp8((int)vv[ks].y, false);
        f32x2 f67 = __builtin_amdgcn_cvt_pk_f32_fp8((int)vv[ks].y, true);
        aa[ks][0] = f2bf(bf2f(sv[ks][0]) - f01.x);
        aa[ks][1] = f2bf(bf2f(sv[ks][1]) - f01.y);
        aa[ks][2] = f2bf(bf2f(sv[ks][2]) - f23.x);
        aa[ks][3] = f2bf(bf2f(sv[ks][3]) - f23.y);
        aa[ks][4] = f2bf(bf2f(sv[ks][4]) - f45.x);
        aa[ks][5] = f2bf(bf2f(sv[ks][5]) - f45.y);
        aa[ks][6] = f2bf(bf2f(sv[ks][6]) - f67.x);
        aa[ks][7] = f2bf(bf2f(sv[ks][7]) - f67.y);
      }
    } else {
      aa[0] = sv[0];  // e half-fragments (prefetched at c-1)
      aa[1] = sv[1];
    }
    // prefetch chunk c+1 operands (all contiguous wave transactions)
    if (c + 1 < 16) {
      int l = (c + 1) >> 1, h = (c + 1) & 1;
      #pragma unroll
      for (int ks = 0; ks < 2; ++ks) {
        sv[ks] = *(const short8*)(
            SBf + (((size_t)l * 512 + rowtile) * 256 + h * 128 + ks * 64 + lane) * 8);
        vv[ks] = *(const uint2*)(
            VBf + (((size_t)(i * 8 + l) * 512 + rowtile) * 256 + h * 128 +
                   ks * 64 + lane) * 8);
      }
    } else if (c + 1 < 18) {
      int h = c + 1 - 16;
      #pragma unroll
      for (int ks = 0; ks < 2; ++ks)
        sv[ks] = *(const short8*)(
            eA + (((size_t)i * 512 + rowtile) * 256 + h * 128 + ks * 64 + lane) * 8);
    }
    const short* bw = BW[c & 1];
    #pragma unroll
    for (int ks = 0; ks < 2; ++ks)
      #pragma unroll
      for (int m = 0; m < 8; ++m) {
        short8 b = *(const short8*)(bw + (m * 16 + lr) * 64 +
                                    (((ks * 4 + kg) ^ lr8) << 3));
        hacc[m] = mfma16(aa[ks], b, hacc[m]);
      }
  }
#undef STAGE_W1

  // epilogue: h = relu(hacc + b1); out = h . W2 + b2
  float sacc[4] = {0.f, 0.f, 0.f, 0.f};
  #pragma unroll
  for (int m = 0; m < 8; ++m) {
    int col = m * 16 + lr;
    float b1v = b1[i * 128 + col];
    float w2v = W2[i * 128 + col];
    #pragma unroll
    for (int r = 0; r < 4; ++r) {
      float h = hacc[m][r] + b1v;
      h = h > 0.f ? h : 0.f;
      sacc[r] += h * w2v;
    }
  }
  #pragma unroll
  for (int r = 0; r < 4; ++r) {
    float v = sacc[r];
    v += __shfl_xor(v, 1);
    v += __shfl_xor(v, 2);
    v += __shfl_xor(v, 4);
    v += __shfl_xor(v, 8);
    if (lr == 0) out[i * 8192 + rowbase + kg * 4 + r] = v + b2[i];
  }
}

extern "C" void kernel_launch(void* const* d_in, const int* in_sizes, int n_in,
                              void* d_out, int out_size, void* d_ws, size_t ws_size,
                              hipStream_t stream) {
  const float* obs = (const float*)d_in[0];
  const float* act = (const float*)d_in[1];
  const float* Wg  = (const float*)d_in[2];
  const float* bg  = (const float*)d_in[3];
  // d_in[4..7] = Wq,bq,Wk,bk: dead (softmax over singleton axis == 1)
  const float* Wv  = (const float*)d_in[8];
  const float* bv  = (const float*)d_in[9];
  const float* W1  = (const float*)d_in[10];
  const float* b1  = (const float*)d_in[11];
  const float* W2  = (const float*)d_in[12];
  const float* b2  = (const float*)d_in[13];
  float* out = (float*)d_out;

  const size_t E_N = (size_t)8 * 8192 * 128;    // eA / SBf shorts (8.4M each)
  const size_t V_B = (size_t)64 * 8192 * 128;   // VBf BYTES (fp8, 67.1 MB)
  // ws proven >= 170 MB (R11/R12 fast path ran); need here ~104 MB.

  short* eA  = (short*)d_ws;
  unsigned char* VBf = (unsigned char*)(eA + E_N);
  short* SBf = (short*)(VBf + V_B);
  short* WgT = SBf + E_N;
  short* WvP = WgT + 163840;
  short* W1P = WvP + 131072;

  k0_tr<<<720, 256, 0, stream>>>(Wg, Wv, W1, WgT, WvP, W1P);
  k1_e<<<dim3(128, 8), 256, 0, stream>>>(obs, act, WgT, bg, eA);
  k2_V<<<1024, 256, 0, stream>>>(eA, WvP, bv, SBf, VBf);
  k3_h<<<1024, 256, 0, stream>>>(eA, SBf, VBf, W1P, b1, W2, b2, out);
}